// Round 8
// baseline (128039.453 us; speedup 1.0000x reference)
//
#include <hip/hip_runtime.h>
#include <math.h>

#define N_ROWS 10816   // 64 * 169 rows per timestep
#define T_SEQ 55
#define NPIX 169

__device__ __forceinline__ float sigmoidf_(float x){ return 1.0f/(1.0f+expf(-x)); }

__device__ __forceinline__ unsigned short f2bf(float f){
    unsigned u = __float_as_uint(f);
    unsigned r = u + 0x7FFFu + ((u>>16)&1u);
    return (unsigned short)(r>>16);
}
__device__ __forceinline__ float bf2f(unsigned short h){
    return __uint_as_float(((unsigned)h)<<16);
}

typedef __attribute__((ext_vector_type(8))) short bfrag;
typedef __attribute__((ext_vector_type(4))) float facc;

// ---------------------------------------------------------------------------
// Kernel 1: fused input transpose + 4x (1x1 conv + ReLU) chain. (unchanged)
// ---------------------------------------------------------------------------
__global__ __launch_bounds__(256) void conv1x1_chain(
    const float* __restrict__ x,
    const float* __restrict__ w0, const float* __restrict__ b0,
    const float* __restrict__ w1, const float* __restrict__ b1,
    const float* __restrict__ w2, const float* __restrict__ b2,
    const float* __restrict__ w3, const float* __restrict__ b3,
    float* __restrict__ out)
{
    int n = blockIdx.x*256 + threadIdx.x;
    int l = blockIdx.y;
    if (n >= N_ROWS) return;
    const float* xp = x + ((size_t)n*T_SEQ + l)*24;
    float in24[24];
    #pragma unroll
    for (int i=0;i<6;i++){
        float4 v = *(const float4*)(xp + 4*i);
        in24[4*i]=v.x; in24[4*i+1]=v.y; in24[4*i+2]=v.z; in24[4*i+3]=v.w;
    }
    float a[30], c[30];
    #pragma unroll
    for (int co=0;co<30;co++) a[co]=b0[co];
    #pragma unroll
    for (int ci=0;ci<24;ci++){
        float v = in24[ci];
        #pragma unroll
        for (int co=0;co<30;co++) a[co] = fmaf(v, w0[ci*30+co], a[co]);
    }
    #pragma unroll
    for (int co=0;co<30;co++) a[co] = fmaxf(a[co],0.f);

#define LAYER30(wp, bp) \
    { _Pragma("unroll") for (int co=0;co<30;co++) c[co]=(bp)[co]; \
      _Pragma("unroll") for (int ci=0;ci<30;ci++){ float v=a[ci]; \
        _Pragma("unroll") for (int co=0;co<30;co++) c[co]=fmaf(v,(wp)[ci*30+co],c[co]); } \
      _Pragma("unroll") for (int co=0;co<30;co++) a[co]=fmaxf(c[co],0.f); }

    LAYER30(w1,b1);
    LAYER30(w2,b2);
    LAYER30(w3,b3);
#undef LAYER30

    float* op = out + (size_t)l*30*N_ROWS + n;
    #pragma unroll
    for (int co=0;co<30;co++) op[(size_t)co*N_ROWS] = a[co];
}

// ---------------------------------------------------------------------------
// Kernel 2: 5x5 SAME conv + ReLU, channel-major, IN-PLACE. (unchanged)
// ---------------------------------------------------------------------------
__global__ __launch_bounds__(192) void conv5x5(
    float* __restrict__ buf, const float* __restrict__ w,
    const float* __restrict__ bias)
{
    __shared__ float img[15*289];
    int bi = blockIdx.x;
    int l = bi >> 6;
    int b = bi & 63;
    float* ip = buf + (size_t)l*30*N_ROWS + (size_t)b*NPIX;
    int tid = threadIdx.x;

    int p = tid;
    bool act = p < 169;
    int pc = act ? p : 0;
    int y = pc/13, x0 = pc - y*13;

    float acc[30];
    #pragma unroll
    for (int co=0;co<30;co++) acc[co]=bias[co];

    for (int i = tid; i < 15*289; i += 192) img[i] = 0.f;

    for (int half = 0; half < 2; half++){
        __syncthreads();
        for (int i = tid; i < 15*169; i += 192){
            int ci = i/169, pp = i - ci*169;
            int yy = pp/13, xx = pp - yy*13;
            img[ci*289 + (yy+2)*17 + (xx+2)] =
                ip[(size_t)(half*15 + ci)*N_ROWS + pp];
        }
        __syncthreads();
        for (int dy=0; dy<5; dy++){
          for (int dx=0; dx<5; dx++){
            const float* wp = w + (size_t)((dy*5+dx)*30 + half*15)*30;
            const float* im = img + (y+dy)*17 + (x0+dx);
            #pragma unroll
            for (int ci=0; ci<15; ci++){
              float v = im[ci*289];
              #pragma unroll
              for (int co=0;co<30;co++) acc[co] = fmaf(v, wp[ci*30+co], acc[co]);
            }
          }
        }
    }
    if (act){
      #pragma unroll
      for (int co=0;co<30;co++) ip[(size_t)co*N_ROWS + p] = fmaxf(acc[co],0.f);
    }
}

// ---------------------------------------------------------------------------
// Kernel 3: MFMA weight repack, bf16 hi/lo split.
// B-frag layout for mfma_f32_16x16x32_bf16: lane holds B[k][n] with
// n = lane&15, k = kt*32 + (lane>>4)*8 + j. Col-tile ct = cell_tile*4 + g
// (g in TF gate order i,j,f,o); cell = cell_tile*16 + n, W col = g*100+cell.
// Cells padded 100->112 (7 tiles), K padded 130->160 / 200->224, pads = 0.
// Frag storage: [(kt*28+ct)*64 + lane]*8 + j  (1 KB per frag, a wave reads
// it as lane*16B -> one coalesced 1024 B load).
// ---------------------------------------------------------------------------
__global__ __launch_bounds__(256) void repack_mfma(
    const float* __restrict__ l1w, const float* __restrict__ l1b,
    const float* __restrict__ l2w, const float* __restrict__ l2b,
    unsigned short* __restrict__ bw1h, unsigned short* __restrict__ bw1l,
    unsigned short* __restrict__ bw2h, unsigned short* __restrict__ bw2l,
    float* __restrict__ pbias1, float* __restrict__ pbias2)
{
    const int S1 = 5*28*512;   // 71680
    const int S2 = 7*28*512;   // 100352
    int i = blockIdx.x*256 + threadIdx.x;
    if (i < S1){
        int fr = i >> 9, r = i & 511;
        int kt = fr/28, ct = fr - kt*28;
        int lane = r >> 3, j = r & 7;
        int k = kt*32 + ((lane>>4)<<3) + j;
        int n = lane & 15;
        int cell = ((ct>>2)<<4) + n, g = ct & 3;
        float w = (k<130 && cell<100) ? l1w[(size_t)k*400 + g*100 + cell] : 0.f;
        unsigned short h = f2bf(w);
        bw1h[i] = h; bw1l[i] = f2bf(w - bf2f(h));
    } else if (i < S1 + S2){
        int ii = i - S1;
        int fr = ii >> 9, r = ii & 511;
        int kt = fr/28, ct = fr - kt*28;
        int lane = r >> 3, j = r & 7;
        int k = kt*32 + ((lane>>4)<<3) + j;
        int n = lane & 15;
        int cell = ((ct>>2)<<4) + n, g = ct & 3;
        float w = (k<200 && cell<100) ? l2w[(size_t)k*400 + g*100 + cell] : 0.f;
        unsigned short h = f2bf(w);
        bw2h[ii] = h; bw2l[ii] = f2bf(w - bf2f(h));
    } else if (i < S1+S2+448){
        int col = i - S1 - S2;
        int ct = col >> 4, n = col & 15;
        int cell = ((ct>>2)<<4) + n, g = ct & 3;
        pbias1[col] = (cell<100) ? l1b[g*100+cell] : 0.f;
    } else if (i < S1+S2+896){
        int col = i - S1 - S2 - 448;
        int ct = col >> 4, n = col & 15;
        int cell = ((ct>>2)<<4) + n, g = ct & 3;
        pbias2[col] = (cell<100) ? l2b[g*100+cell] : 0.f;
    }
}

// ---------------------------------------------------------------------------
// Kernel 4: PERSISTENT 2-layer LSTM + projection via split-bf16 MFMA.
// Block = 16 rows (one M-tile), 4 waves; wave w owns cell-tiles
// {2w, 2w+1} (wave3: tile 6 only). z = Ah·Bh + Ah·Bl + Al·Bh + Al·Bl
// (rep error ~2^-17 each operand). A kept fp32 in LDS ([m][k], k-major,
// KP pad chosen so strided writes are <=2-way bank conflicts), converted
// to bf16 hi/lo frags at read. C/D layout: lane = (col=cell, 4 rows) ->
// all 4 gates of a cell in-lane; c-state in VGPRs; h written back to A
// arrays for the next GEMMs. 6 barriers/step. Grid 676 x 256.
// ---------------------------------------------------------------------------
#define KP1 164
#define KP2 228
__global__ __launch_bounds__(256) void lstm_mfma(
    const float* __restrict__ xall,   // [55][30][N]
    const unsigned short* __restrict__ bw1h, const unsigned short* __restrict__ bw1l,
    const unsigned short* __restrict__ bw2h, const unsigned short* __restrict__ bw2l,
    const float* __restrict__ pbias1, const float* __restrict__ pbias2,
    const float* __restrict__ we, const float* __restrict__ be,
    float* __restrict__ out)          // [N][55]
{
    __shared__ float A1[16*KP1];      // [m][k]: k<30 x_t, 30..129 h1, pad->163
    __shared__ float A2[16*KP2];      // [m][k]: k<100 h1new, 100..199 h2, pad->227
    __shared__ float pbuf[128];

    const int tid  = threadIdx.x;
    const int wave = tid >> 6, lane = tid & 63;
    const int m16  = lane & 15, quad = lane >> 4;
    const int n0   = blockIdx.x * 16;
    const int ct0  = wave*2;
    const int ntile = (wave<3) ? 2 : 1;

    for (int i=tid; i<16*KP1; i+=256) A1[i]=0.f;
    for (int i=tid; i<16*KP2; i+=256) A2[i]=0.f;

    float cs1[2][4] = {{0,0,0,0},{0,0,0,0}};
    float cs2[2][4] = {{0,0,0,0},{0,0,0,0}};
    float b1r[2][4], b2r[2][4];
    for (int tb=0; tb<2; tb++)
      for (int g=0; g<4; g++){
        if (tb < ntile){
          int col = ((ct0+tb)*4+g)*16 + m16;
          b1r[tb][g] = pbias1[col];
          b2r[tb][g] = pbias2[col];
        } else { b1r[tb][g]=0.f; b2r[tb][g]=0.f; }
      }
    __syncthreads();

    bfrag ah[7], al[7];
    facc acc[2][4];

#define LOAD_AFRAGS(ABUF, KP, NKT) \
    for (int kt=0; kt<(NKT); kt++){ \
        float av[8]; \
        const float* ap = (ABUF) + m16*(KP) + kt*32 + quad*8; \
        *(float4*)(av)   = *(const float4*)ap; \
        *(float4*)(av+4) = *(const float4*)(ap+4); \
        _Pragma("unroll") \
        for (int e=0;e<8;e++){ \
            unsigned short hh = f2bf(av[e]); \
            ah[kt][e] = (short)hh; \
            al[kt][e] = (short)f2bf(av[e] - bf2f(hh)); \
        } \
    }

#define MFMA_LAYER(WH, WL, NKT, BR) \
    for (int tb=0; tb<ntile; tb++){ \
        _Pragma("unroll") \
        for (int g=0;g<4;g++){ float bb=(BR)[tb][g]; acc[tb][g]=(facc){bb,bb,bb,bb}; } \
    } \
    for (int kt=0; kt<(NKT); kt++) \
      for (int tb=0; tb<ntile; tb++){ \
        _Pragma("unroll") \
        for (int g=0; g<4; g++){ \
          size_t base = ((size_t)((kt*28 + (ct0+tb)*4 + g)*64 + lane))*8; \
          bfrag bh = *(const bfrag*)((WH) + base); \
          bfrag bl = *(const bfrag*)((WL) + base); \
          acc[tb][g] = __builtin_amdgcn_mfma_f32_16x16x32_bf16(ah[kt], bh, acc[tb][g],0,0,0); \
          acc[tb][g] = __builtin_amdgcn_mfma_f32_16x16x32_bf16(al[kt], bh, acc[tb][g],0,0,0); \
          acc[tb][g] = __builtin_amdgcn_mfma_f32_16x16x32_bf16(ah[kt], bl, acc[tb][g],0,0,0); \
          acc[tb][g] = __builtin_amdgcn_mfma_f32_16x16x32_bf16(al[kt], bl, acc[tb][g],0,0,0); \
        } \
      }

    for (int t=0; t<T_SEQ; t++){
        // P1: stage x_t into A1 (k<30), transposed to [m][k]
        if (tid < 120){
            int k = tid >> 2, q = tid & 3;
            float4 v = *(const float4*)(xall + ((size_t)t*30+k)*N_ROWS + n0 + q*4);
            A1[(q*4+0)*KP1 + k] = v.x;
            A1[(q*4+1)*KP1 + k] = v.y;
            A1[(q*4+2)*KP1 + k] = v.z;
            A1[(q*4+3)*KP1 + k] = v.w;
        }
        __syncthreads();                                   // B1

        // P2: layer 1 GEMM
        LOAD_AFRAGS(A1, KP1, 5);
        MFMA_LAYER(bw1h, bw1l, 5, b1r);
        __syncthreads();                                   // B2

        // P3: gates layer 1 -> h1 into A1 (recurrence) and A2 (layer2 input)
        for (int tb=0; tb<ntile; tb++){
            int cell = (ct0+tb)*16 + m16;
            #pragma unroll
            for (int i2=0;i2<4;i2++){
                float gi = sigmoidf_(acc[tb][0][i2]);
                float gj = tanhf(acc[tb][1][i2]);
                float gf = sigmoidf_(acc[tb][2][i2] + 1.0f);
                float go = sigmoidf_(acc[tb][3][i2]);
                float cn = gf*cs1[tb][i2] + gi*gj;
                cs1[tb][i2] = cn;
                float h = go*tanhf(cn);
                if (cell < 100){
                    int m = quad*4 + i2;
                    A1[m*KP1 + 30 + cell] = h;
                    A2[m*KP2 + cell] = h;
                }
            }
        }
        __syncthreads();                                   // B3

        // P4: layer 2 GEMM
        LOAD_AFRAGS(A2, KP2, 7);
        MFMA_LAYER(bw2h, bw2l, 7, b2r);
        __syncthreads();                                   // B4

        // P5: gates layer 2 -> h2 into A2
        for (int tb=0; tb<ntile; tb++){
            int cell = (ct0+tb)*16 + m16;
            #pragma unroll
            for (int i2=0;i2<4;i2++){
                float gi = sigmoidf_(acc[tb][0][i2]);
                float gj = tanhf(acc[tb][1][i2]);
                float gf = sigmoidf_(acc[tb][2][i2] + 1.0f);
                float go = sigmoidf_(acc[tb][3][i2]);
                float cn = gf*cs2[tb][i2] + gi*gj;
                cs2[tb][i2] = cn;
                float h = go*tanhf(cn);
                if (cell < 100){
                    int m = quad*4 + i2;
                    A2[m*KP2 + 100 + cell] = h;
                }
            }
        }
        __syncthreads();                                   // B5

        // P6: fused 1x1 projection out[n][t] = h2 . we + be
        if (tid < 128){
            int r = tid & 15, s = tid >> 4;
            int cb = s*13, ce = (s==7) ? 100 : cb+13;
            float p = 0.f;
            for (int cc=cb; cc<ce; cc++)
                p = fmaf(A2[r*KP2 + 100 + cc], we[cc], p);
            pbuf[tid] = p;
        }
        __syncthreads();                                   // B6
        if (tid < 16){
            float s = be[0];
            #pragma unroll
            for (int q2=0;q2<8;q2++) s += pbuf[q2*16 + tid];
            out[(size_t)(n0+tid)*T_SEQ + t] = s;
        }
    }
#undef LOAD_AFRAGS
#undef MFMA_LAYER
}

// ---------------------------------------------------------------------------
extern "C" void kernel_launch(void* const* d_in, const int* in_sizes, int n_in,
                              void* d_out, int out_size, void* d_ws, size_t ws_size,
                              hipStream_t stream)
{
    const float* x    = (const float*)d_in[0];
    const float* w10  = (const float*)d_in[1];  const float* b10 = (const float*)d_in[2];
    const float* w11  = (const float*)d_in[3];  const float* b11 = (const float*)d_in[4];
    const float* w12  = (const float*)d_in[5];  const float* b12 = (const float*)d_in[6];
    const float* w13  = (const float*)d_in[7];  const float* b13 = (const float*)d_in[8];
    const float* w20  = (const float*)d_in[9];  const float* b20 = (const float*)d_in[10];
    const float* w21  = (const float*)d_in[11]; const float* b21 = (const float*)d_in[12];
    const float* w22  = (const float*)d_in[13]; const float* b22 = (const float*)d_in[14];
    const float* w23  = (const float*)d_in[15]; const float* b23 = (const float*)d_in[16];
    const float* l1w  = (const float*)d_in[17]; const float* l1b = (const float*)d_in[18];
    const float* l2w  = (const float*)d_in[19]; const float* l2b = (const float*)d_in[20];
    const float* we   = (const float*)d_in[21]; const float* be  = (const float*)d_in[22];
    float* out = (float*)d_out;

    // workspace: conv slab 71.4 MB + packed bf16 weights ~0.7 MB + biases
    const size_t NF = (size_t)30*N_ROWS;
    float* buf0 = (float*)d_ws;                       // [55][30][N] floats
    unsigned short* bw1h = (unsigned short*)(buf0 + (size_t)T_SEQ*NF);
    unsigned short* bw1l = bw1h + 5*28*512;           // 71680 each
    unsigned short* bw2h = bw1l + 5*28*512;
    unsigned short* bw2l = bw2h + 7*28*512;           // 100352 each
    float* pbias1 = (float*)(bw2l + 7*28*512);
    float* pbias2 = pbias1 + 448;

    const int REPACK_N = 5*28*512 + 7*28*512 + 896;
    repack_mfma<<<(REPACK_N+255)/256, 256, 0, stream>>>(
        l1w, l1b, l2w, l2b, bw1h, bw1l, bw2h, bw2l, pbias1, pbias2);

    dim3 g1((N_ROWS+255)/256, T_SEQ);
    conv1x1_chain<<<g1, 256, 0, stream>>>(x, w10,b10, w11,b11, w12,b12, w13,b13, buf0);
    conv5x5<<<T_SEQ*64, 192, 0, stream>>>(buf0, w20, b20);
    conv5x5<<<T_SEQ*64, 192, 0, stream>>>(buf0, w21, b21);
    conv5x5<<<T_SEQ*64, 192, 0, stream>>>(buf0, w22, b22);
    conv5x5<<<T_SEQ*64, 192, 0, stream>>>(buf0, w23, b23);

    lstm_mfma<<<N_ROWS/16, 256, 0, stream>>>(buf0, bw1h, bw1l, bw2h, bw2l,
                                             pbias1, pbias2, we, be, out);
}

// Round 9
// 5693.666 us; speedup vs baseline: 22.4881x; 22.4881x over previous
//
#include <hip/hip_runtime.h>
#include <math.h>

#define N_ROWS 10816   // 64 * 169 rows per timestep
#define T_SEQ 55
#define NPIX 169

__device__ __forceinline__ float sigmoidf_(float x){ return 1.0f/(1.0f+expf(-x)); }

__device__ __forceinline__ unsigned short f2bf(float f){
    unsigned u = __float_as_uint(f);
    unsigned r = u + 0x7FFFu + ((u>>16)&1u);
    return (unsigned short)(r>>16);
}
__device__ __forceinline__ float bf2f(unsigned short h){
    return __uint_as_float(((unsigned)h)<<16);
}

typedef __attribute__((ext_vector_type(8))) short bfrag;
typedef __attribute__((ext_vector_type(4))) float facc;

// ---------------------------------------------------------------------------
// Kernel 1: fused input transpose + 4x (1x1 conv + ReLU) chain. (unchanged)
// ---------------------------------------------------------------------------
__global__ __launch_bounds__(256) void conv1x1_chain(
    const float* __restrict__ x,
    const float* __restrict__ w0, const float* __restrict__ b0,
    const float* __restrict__ w1, const float* __restrict__ b1,
    const float* __restrict__ w2, const float* __restrict__ b2,
    const float* __restrict__ w3, const float* __restrict__ b3,
    float* __restrict__ out)
{
    int n = blockIdx.x*256 + threadIdx.x;
    int l = blockIdx.y;
    if (n >= N_ROWS) return;
    const float* xp = x + ((size_t)n*T_SEQ + l)*24;
    float in24[24];
    #pragma unroll
    for (int i=0;i<6;i++){
        float4 v = *(const float4*)(xp + 4*i);
        in24[4*i]=v.x; in24[4*i+1]=v.y; in24[4*i+2]=v.z; in24[4*i+3]=v.w;
    }
    float a[30], c[30];
    #pragma unroll
    for (int co=0;co<30;co++) a[co]=b0[co];
    #pragma unroll
    for (int ci=0;ci<24;ci++){
        float v = in24[ci];
        #pragma unroll
        for (int co=0;co<30;co++) a[co] = fmaf(v, w0[ci*30+co], a[co]);
    }
    #pragma unroll
    for (int co=0;co<30;co++) a[co] = fmaxf(a[co],0.f);

#define LAYER30(wp, bp) \
    { _Pragma("unroll") for (int co=0;co<30;co++) c[co]=(bp)[co]; \
      _Pragma("unroll") for (int ci=0;ci<30;ci++){ float v=a[ci]; \
        _Pragma("unroll") for (int co=0;co<30;co++) c[co]=fmaf(v,(wp)[ci*30+co],c[co]); } \
      _Pragma("unroll") for (int co=0;co<30;co++) a[co]=fmaxf(c[co],0.f); }

    LAYER30(w1,b1);
    LAYER30(w2,b2);
    LAYER30(w3,b3);
#undef LAYER30

    float* op = out + (size_t)l*30*N_ROWS + n;
    #pragma unroll
    for (int co=0;co<30;co++) op[(size_t)co*N_ROWS] = a[co];
}

// ---------------------------------------------------------------------------
// Kernel 2: 5x5 SAME conv + ReLU, channel-major, IN-PLACE. (unchanged)
// ---------------------------------------------------------------------------
__global__ __launch_bounds__(192) void conv5x5(
    float* __restrict__ buf, const float* __restrict__ w,
    const float* __restrict__ bias)
{
    __shared__ float img[15*289];
    int bi = blockIdx.x;
    int l = bi >> 6;
    int b = bi & 63;
    float* ip = buf + (size_t)l*30*N_ROWS + (size_t)b*NPIX;
    int tid = threadIdx.x;

    int p = tid;
    bool act = p < 169;
    int pc = act ? p : 0;
    int y = pc/13, x0 = pc - y*13;

    float acc[30];
    #pragma unroll
    for (int co=0;co<30;co++) acc[co]=bias[co];

    for (int i = tid; i < 15*289; i += 192) img[i] = 0.f;

    for (int half = 0; half < 2; half++){
        __syncthreads();
        for (int i = tid; i < 15*169; i += 192){
            int ci = i/169, pp = i - ci*169;
            int yy = pp/13, xx = pp - yy*13;
            img[ci*289 + (yy+2)*17 + (xx+2)] =
                ip[(size_t)(half*15 + ci)*N_ROWS + pp];
        }
        __syncthreads();
        for (int dy=0; dy<5; dy++){
          for (int dx=0; dx<5; dx++){
            const float* wp = w + (size_t)((dy*5+dx)*30 + half*15)*30;
            const float* im = img + (y+dy)*17 + (x0+dx);
            #pragma unroll
            for (int ci=0; ci<15; ci++){
              float v = im[ci*289];
              #pragma unroll
              for (int co=0;co<30;co++) acc[co] = fmaf(v, wp[ci*30+co], acc[co]);
            }
          }
        }
    }
    if (act){
      #pragma unroll
      for (int co=0;co<30;co++) ip[(size_t)co*N_ROWS + p] = fmaxf(acc[co],0.f);
    }
}

// ---------------------------------------------------------------------------
// Kernel 3: MFMA weight repack, bf16 hi/lo split. Cells padded 100->128
// (8 cell-tiles -> every wave owns exactly 2: compile-time trip counts, the
// R8 scratch-spill fix). Col-tile ct = cell_tile*4 + g; frag id =
// kt*32 + ct; lane holds B[k][n], n=lane&15, k=kt*32+(lane>>4)*8+j.
// Storage: [frag*64 + lane]*8 + j (1 KB/frag -> one coalesced wave load).
// ---------------------------------------------------------------------------
__global__ __launch_bounds__(256) void repack_mfma(
    const float* __restrict__ l1w, const float* __restrict__ l1b,
    const float* __restrict__ l2w, const float* __restrict__ l2b,
    unsigned short* __restrict__ bw1h, unsigned short* __restrict__ bw1l,
    unsigned short* __restrict__ bw2h, unsigned short* __restrict__ bw2l,
    float* __restrict__ pbias1, float* __restrict__ pbias2)
{
    const int S1 = 5*32*512;   // 81920
    const int S2 = 7*32*512;   // 114688
    int i = blockIdx.x*256 + threadIdx.x;
    if (i < S1){
        int fr = i >> 9, r = i & 511;
        int kt = fr >> 5, ct = fr & 31;
        int lane = r >> 3, j = r & 7;
        int k = kt*32 + ((lane>>4)<<3) + j;
        int n = lane & 15;
        int cell = ((ct>>2)<<4) + n, g = ct & 3;
        float w = (k<130 && cell<100) ? l1w[(size_t)k*400 + g*100 + cell] : 0.f;
        unsigned short h = f2bf(w);
        bw1h[i] = h; bw1l[i] = f2bf(w - bf2f(h));
    } else if (i < S1 + S2){
        int ii = i - S1;
        int fr = ii >> 9, r = ii & 511;
        int kt = fr >> 5, ct = fr & 31;
        int lane = r >> 3, j = r & 7;
        int k = kt*32 + ((lane>>4)<<3) + j;
        int n = lane & 15;
        int cell = ((ct>>2)<<4) + n, g = ct & 3;
        float w = (k<200 && cell<100) ? l2w[(size_t)k*400 + g*100 + cell] : 0.f;
        unsigned short h = f2bf(w);
        bw2h[ii] = h; bw2l[ii] = f2bf(w - bf2f(h));
    } else if (i < S1+S2+512){
        int col = i - S1 - S2;
        int ct = col >> 4, n = col & 15;
        int cell = ((ct>>2)<<4) + n, g = ct & 3;
        pbias1[col] = (cell<100) ? l1b[g*100+cell] : 0.f;
    } else if (i < S1+S2+1024){
        int col = i - S1 - S2 - 512;
        int ct = col >> 4, n = col & 15;
        int cell = ((ct>>2)<<4) + n, g = ct & 3;
        pbias2[col] = (cell<100) ? l2b[g*100+cell] : 0.f;
    }
}

// ---------------------------------------------------------------------------
// Kernel 4: PERSISTENT 2-layer LSTM + projection via split-bf16 MFMA, v2.
// R8 spilled acc/frag arrays to scratch (runtime ntile blocked unrolling ->
// dynamic indexing -> 150 ms). Fix: every wave owns exactly 2 cell-tiles
// (N padded to 512), ALL hot loops have literal bounds + #pragma unroll,
// A-frag conversion fused into the kt loop (one live hi/lo pair).
// z = Ah·Bh + Al·Bh + Ah·Bl + Al·Bl. A fp32 in LDS [m][k] (pad 164/228:
// stride mod 32 banks = 4 -> 2-way, free). C/D: col=lane&15 (cell),
// row=quad*4+reg -> all 4 gates in-lane, c-state in VGPRs. Grid 676 x 256.
// ---------------------------------------------------------------------------
#define KP1 164
#define KP2 228
__global__ __launch_bounds__(256) void lstm_mfma2(
    const float* __restrict__ xall,   // [55][30][N]
    const unsigned short* __restrict__ bw1h, const unsigned short* __restrict__ bw1l,
    const unsigned short* __restrict__ bw2h, const unsigned short* __restrict__ bw2l,
    const float* __restrict__ pbias1, const float* __restrict__ pbias2,
    const float* __restrict__ we, const float* __restrict__ be,
    float* __restrict__ out)          // [N][55]
{
    __shared__ float A1[16*KP1];      // [m][k]: k<30 x_t, 30..129 h1, pad 0
    __shared__ float A2[16*KP2];      // [m][k]: k<100 h1new, 100..199 h2, pad 0
    __shared__ float pbuf[128];

    const int tid  = threadIdx.x;
    const int wave = tid >> 6, lane = tid & 63;
    const int m16  = lane & 15, quad = lane >> 4;
    const int n0   = blockIdx.x * 16;
    const int cl0  = wave*2;              // my 2 cell-tiles: cl0, cl0+1
    const int cell0 = cl0*16 + m16;
    const int cell1 = cell0 + 16;

    for (int i=tid; i<16*KP1; i+=256) A1[i]=0.f;
    for (int i=tid; i<16*KP2; i+=256) A2[i]=0.f;

    float cs1a[4]={0,0,0,0}, cs1b[4]={0,0,0,0};
    float cs2a[4]={0,0,0,0}, cs2b[4]={0,0,0,0};
    float b1a[4], b1b[4], b2a[4], b2b[4];
    #pragma unroll
    for (int g=0; g<4; g++){
        b1a[g] = pbias1[(cl0*4+g)*16 + m16];
        b1b[g] = pbias1[((cl0+1)*4+g)*16 + m16];
        b2a[g] = pbias2[(cl0*4+g)*16 + m16];
        b2b[g] = pbias2[((cl0+1)*4+g)*16 + m16];
    }
    __syncthreads();

    facc acA[4], acB[4];

// GEMM over NKT k-tiles; acc tiles acA (cl0) and acB (cl0+1). All trip
// counts literal -> full unroll -> everything stays in registers.
#define GEMM(WH, WL, NKT, ABUF, KP, BIA, BIB) \
    { _Pragma("unroll") \
      for (int g=0; g<4; g++){ \
          acA[g]=(facc){(BIA)[g],(BIA)[g],(BIA)[g],(BIA)[g]}; \
          acB[g]=(facc){(BIB)[g],(BIB)[g],(BIB)[g],(BIB)[g]}; } \
      _Pragma("unroll") \
      for (int kt=0; kt<(NKT); kt++){ \
        float av[8]; \
        const float* ap = (ABUF) + m16*(KP) + kt*32 + quad*8; \
        *(float4*)(av)   = *(const float4*)ap; \
        *(float4*)(av+4) = *(const float4*)(ap+4); \
        bfrag ah, al; \
        _Pragma("unroll") \
        for (int e=0;e<8;e++){ \
            unsigned short hh = f2bf(av[e]); \
            ah[e] = (short)hh; \
            al[e] = (short)f2bf(av[e] - bf2f(hh)); } \
        _Pragma("unroll") \
        for (int g=0; g<4; g++){ \
          { const size_t base = ((size_t)((kt*32 + cl0*4 + g)*64 + lane))*8; \
            bfrag bh = *(const bfrag*)((WH) + base); \
            bfrag bl = *(const bfrag*)((WL) + base); \
            acA[g] = __builtin_amdgcn_mfma_f32_16x16x32_bf16(ah, bh, acA[g],0,0,0); \
            acA[g] = __builtin_amdgcn_mfma_f32_16x16x32_bf16(al, bh, acA[g],0,0,0); \
            acA[g] = __builtin_amdgcn_mfma_f32_16x16x32_bf16(ah, bl, acA[g],0,0,0); \
            acA[g] = __builtin_amdgcn_mfma_f32_16x16x32_bf16(al, bl, acA[g],0,0,0); } \
          { const size_t base = ((size_t)((kt*32 + (cl0+1)*4 + g)*64 + lane))*8; \
            bfrag bh = *(const bfrag*)((WH) + base); \
            bfrag bl = *(const bfrag*)((WL) + base); \
            acB[g] = __builtin_amdgcn_mfma_f32_16x16x32_bf16(ah, bh, acB[g],0,0,0); \
            acB[g] = __builtin_amdgcn_mfma_f32_16x16x32_bf16(al, bh, acB[g],0,0,0); \
            acB[g] = __builtin_amdgcn_mfma_f32_16x16x32_bf16(ah, bl, acB[g],0,0,0); \
            acB[g] = __builtin_amdgcn_mfma_f32_16x16x32_bf16(al, bl, acB[g],0,0,0); } \
        } \
      } }

// Gate epilogue for one acc tile; writes h (cells < 100 only).
#define EPI1(AC, CS, CELL) \
    { _Pragma("unroll") \
      for (int i2=0;i2<4;i2++){ \
        float gi = sigmoidf_((AC)[0][i2]); \
        float gj = tanhf((AC)[1][i2]); \
        float gf = sigmoidf_((AC)[2][i2] + 1.0f); \
        float go = sigmoidf_((AC)[3][i2]); \
        float cn = gf*(CS)[i2] + gi*gj; \
        (CS)[i2] = cn; \
        float h = go*tanhf(cn); \
        if ((CELL) < 100){ \
            int m = quad*4 + i2; \
            A1[m*KP1 + 30 + (CELL)] = h; \
            A2[m*KP2 + (CELL)] = h; } } }

#define EPI2(AC, CS, CELL) \
    { _Pragma("unroll") \
      for (int i2=0;i2<4;i2++){ \
        float gi = sigmoidf_((AC)[0][i2]); \
        float gj = tanhf((AC)[1][i2]); \
        float gf = sigmoidf_((AC)[2][i2] + 1.0f); \
        float go = sigmoidf_((AC)[3][i2]); \
        float cn = gf*(CS)[i2] + gi*gj; \
        (CS)[i2] = cn; \
        float h = go*tanhf(cn); \
        if ((CELL) < 100){ \
            int m = quad*4 + i2; \
            A2[m*KP2 + 100 + (CELL)] = h; } } }

    for (int t=0; t<T_SEQ; t++){
        // P1: stage x_t into A1 (k<30), transposed to [m][k]
        if (tid < 120){
            int k = tid >> 2, q = tid & 3;
            float4 v = *(const float4*)(xall + ((size_t)t*30+k)*N_ROWS + n0 + q*4);
            A1[(q*4+0)*KP1 + k] = v.x;
            A1[(q*4+1)*KP1 + k] = v.y;
            A1[(q*4+2)*KP1 + k] = v.z;
            A1[(q*4+3)*KP1 + k] = v.w;
        }
        __syncthreads();                                   // B1

        GEMM(bw1h, bw1l, 5, A1, KP1, b1a, b1b);            // layer 1
        __syncthreads();                                   // B2
        EPI1(acA, cs1a, cell0);
        EPI1(acB, cs1b, cell1);
        __syncthreads();                                   // B3

        GEMM(bw2h, bw2l, 7, A2, KP2, b2a, b2b);            // layer 2
        __syncthreads();                                   // B4
        EPI2(acA, cs2a, cell0);
        EPI2(acB, cs2b, cell1);
        __syncthreads();                                   // B5

        // P6: fused 1x1 projection out[n][t] = h2 . we + be
        if (tid < 128){
            int r = tid & 15, s = tid >> 4;
            int cb = s*13, ce = (s==7) ? 100 : cb+13;
            float p = 0.f;
            for (int cc=cb; cc<ce; cc++)
                p = fmaf(A2[r*KP2 + 100 + cc], we[cc], p);
            pbuf[tid] = p;
        }
        __syncthreads();                                   // B6
        if (tid < 16){
            float s = be[0];
            #pragma unroll
            for (int q2=0;q2<8;q2++) s += pbuf[q2*16 + tid];
            out[(size_t)(n0+tid)*T_SEQ + t] = s;
        }
    }
#undef GEMM
#undef EPI1
#undef EPI2
}

// ---------------------------------------------------------------------------
extern "C" void kernel_launch(void* const* d_in, const int* in_sizes, int n_in,
                              void* d_out, int out_size, void* d_ws, size_t ws_size,
                              hipStream_t stream)
{
    const float* x    = (const float*)d_in[0];
    const float* w10  = (const float*)d_in[1];  const float* b10 = (const float*)d_in[2];
    const float* w11  = (const float*)d_in[3];  const float* b11 = (const float*)d_in[4];
    const float* w12  = (const float*)d_in[5];  const float* b12 = (const float*)d_in[6];
    const float* w13  = (const float*)d_in[7];  const float* b13 = (const float*)d_in[8];
    const float* w20  = (const float*)d_in[9];  const float* b20 = (const float*)d_in[10];
    const float* w21  = (const float*)d_in[11]; const float* b21 = (const float*)d_in[12];
    const float* w22  = (const float*)d_in[13]; const float* b22 = (const float*)d_in[14];
    const float* w23  = (const float*)d_in[15]; const float* b23 = (const float*)d_in[16];
    const float* l1w  = (const float*)d_in[17]; const float* l1b = (const float*)d_in[18];
    const float* l2w  = (const float*)d_in[19]; const float* l2b = (const float*)d_in[20];
    const float* we   = (const float*)d_in[21]; const float* be  = (const float*)d_in[22];
    float* out = (float*)d_out;

    // workspace: conv slab 71.4 MB + packed bf16 weights ~0.8 MB + biases
    const size_t NF = (size_t)30*N_ROWS;
    float* buf0 = (float*)d_ws;                       // [55][30][N] floats
    unsigned short* bw1h = (unsigned short*)(buf0 + (size_t)T_SEQ*NF);
    unsigned short* bw1l = bw1h + 5*32*512;           // 81920 each
    unsigned short* bw2h = bw1l + 5*32*512;
    unsigned short* bw2l = bw2h + 7*32*512;           // 114688 each
    float* pbias1 = (float*)(bw2l + 7*32*512);
    float* pbias2 = pbias1 + 512;

    const int REPACK_N = 5*32*512 + 7*32*512 + 1024;
    repack_mfma<<<(REPACK_N+255)/256, 256, 0, stream>>>(
        l1w, l1b, l2w, l2b, bw1h, bw1l, bw2h, bw2l, pbias1, pbias2);

    dim3 g1((N_ROWS+255)/256, T_SEQ);
    conv1x1_chain<<<g1, 256, 0, stream>>>(x, w10,b10, w11,b11, w12,b12, w13,b13, buf0);
    conv5x5<<<T_SEQ*64, 192, 0, stream>>>(buf0, w20, b20);
    conv5x5<<<T_SEQ*64, 192, 0, stream>>>(buf0, w21, b21);
    conv5x5<<<T_SEQ*64, 192, 0, stream>>>(buf0, w22, b22);
    conv5x5<<<T_SEQ*64, 192, 0, stream>>>(buf0, w23, b23);

    lstm_mfma2<<<N_ROWS/16, 256, 0, stream>>>(buf0, bw1h, bw1l, bw2h, bw2l,
                                              pbias1, pbias2, we, be, out);
}

// Round 10
// 2949.835 us; speedup vs baseline: 43.4056x; 1.9302x over previous
//
#include <hip/hip_runtime.h>
#include <math.h>

#define N_ROWS 10816   // 64 * 169 rows per timestep
#define T_SEQ 55
#define NPIX 169

__device__ __forceinline__ float sigmoidf_(float x){ return 1.0f/(1.0f+expf(-x)); }

__device__ __forceinline__ unsigned short f2bf(float f){
    unsigned u = __float_as_uint(f);
    unsigned r = u + 0x7FFFu + ((u>>16)&1u);
    return (unsigned short)(r>>16);
}
__device__ __forceinline__ float bf2f(unsigned short h){
    return __uint_as_float(((unsigned)h)<<16);
}

typedef __attribute__((ext_vector_type(8))) short bfrag;
typedef __attribute__((ext_vector_type(4))) float facc;

// ---------------------------------------------------------------------------
// Kernel 1: fused input transpose + 4x (1x1 conv + ReLU) chain. (unchanged)
// ---------------------------------------------------------------------------
__global__ __launch_bounds__(256) void conv1x1_chain(
    const float* __restrict__ x,
    const float* __restrict__ w0, const float* __restrict__ b0,
    const float* __restrict__ w1, const float* __restrict__ b1,
    const float* __restrict__ w2, const float* __restrict__ b2,
    const float* __restrict__ w3, const float* __restrict__ b3,
    float* __restrict__ out)
{
    int n = blockIdx.x*256 + threadIdx.x;
    int l = blockIdx.y;
    if (n >= N_ROWS) return;
    const float* xp = x + ((size_t)n*T_SEQ + l)*24;
    float in24[24];
    #pragma unroll
    for (int i=0;i<6;i++){
        float4 v = *(const float4*)(xp + 4*i);
        in24[4*i]=v.x; in24[4*i+1]=v.y; in24[4*i+2]=v.z; in24[4*i+3]=v.w;
    }
    float a[30], c[30];
    #pragma unroll
    for (int co=0;co<30;co++) a[co]=b0[co];
    #pragma unroll
    for (int ci=0;ci<24;ci++){
        float v = in24[ci];
        #pragma unroll
        for (int co=0;co<30;co++) a[co] = fmaf(v, w0[ci*30+co], a[co]);
    }
    #pragma unroll
    for (int co=0;co<30;co++) a[co] = fmaxf(a[co],0.f);

#define LAYER30(wp, bp) \
    { _Pragma("unroll") for (int co=0;co<30;co++) c[co]=(bp)[co]; \
      _Pragma("unroll") for (int ci=0;ci<30;ci++){ float v=a[ci]; \
        _Pragma("unroll") for (int co=0;co<30;co++) c[co]=fmaf(v,(wp)[ci*30+co],c[co]); } \
      _Pragma("unroll") for (int co=0;co<30;co++) a[co]=fmaxf(c[co],0.f); }

    LAYER30(w1,b1);
    LAYER30(w2,b2);
    LAYER30(w3,b3);
#undef LAYER30

    float* op = out + (size_t)l*30*N_ROWS + n;
    #pragma unroll
    for (int co=0;co<30;co++) op[(size_t)co*N_ROWS] = a[co];
}

// ---------------------------------------------------------------------------
// Kernel 2: 5x5 SAME conv + ReLU, channel-major, IN-PLACE. (unchanged)
// ---------------------------------------------------------------------------
__global__ __launch_bounds__(192) void conv5x5(
    float* __restrict__ buf, const float* __restrict__ w,
    const float* __restrict__ bias)
{
    __shared__ float img[15*289];
    int bi = blockIdx.x;
    int l = bi >> 6;
    int b = bi & 63;
    float* ip = buf + (size_t)l*30*N_ROWS + (size_t)b*NPIX;
    int tid = threadIdx.x;

    int p = tid;
    bool act = p < 169;
    int pc = act ? p : 0;
    int y = pc/13, x0 = pc - y*13;

    float acc[30];
    #pragma unroll
    for (int co=0;co<30;co++) acc[co]=bias[co];

    for (int i = tid; i < 15*289; i += 192) img[i] = 0.f;

    for (int half = 0; half < 2; half++){
        __syncthreads();
        for (int i = tid; i < 15*169; i += 192){
            int ci = i/169, pp = i - ci*169;
            int yy = pp/13, xx = pp - yy*13;
            img[ci*289 + (yy+2)*17 + (xx+2)] =
                ip[(size_t)(half*15 + ci)*N_ROWS + pp];
        }
        __syncthreads();
        for (int dy=0; dy<5; dy++){
          for (int dx=0; dx<5; dx++){
            const float* wp = w + (size_t)((dy*5+dx)*30 + half*15)*30;
            const float* im = img + (y+dy)*17 + (x0+dx);
            #pragma unroll
            for (int ci=0; ci<15; ci++){
              float v = im[ci*289];
              #pragma unroll
              for (int co=0;co<30;co++) acc[co] = fmaf(v, wp[ci*30+co], acc[co]);
            }
          }
        }
    }
    if (act){
      #pragma unroll
      for (int co=0;co<30;co++) ip[(size_t)co*N_ROWS + p] = fmaxf(acc[co],0.f);
    }
}

// ---------------------------------------------------------------------------
// Kernel 3: MFMA weight repack, bf16 hi/lo split. (unchanged from R9)
// Cells padded 100->128 (8 cell-tiles, 2/wave, compile-time trip counts).
// ---------------------------------------------------------------------------
__global__ __launch_bounds__(256) void repack_mfma(
    const float* __restrict__ l1w, const float* __restrict__ l1b,
    const float* __restrict__ l2w, const float* __restrict__ l2b,
    unsigned short* __restrict__ bw1h, unsigned short* __restrict__ bw1l,
    unsigned short* __restrict__ bw2h, unsigned short* __restrict__ bw2l,
    float* __restrict__ pbias1, float* __restrict__ pbias2)
{
    const int S1 = 5*32*512;   // 81920
    const int S2 = 7*32*512;   // 114688
    int i = blockIdx.x*256 + threadIdx.x;
    if (i < S1){
        int fr = i >> 9, r = i & 511;
        int kt = fr >> 5, ct = fr & 31;
        int lane = r >> 3, j = r & 7;
        int k = kt*32 + ((lane>>4)<<3) + j;
        int n = lane & 15;
        int cell = ((ct>>2)<<4) + n, g = ct & 3;
        float w = (k<130 && cell<100) ? l1w[(size_t)k*400 + g*100 + cell] : 0.f;
        unsigned short h = f2bf(w);
        bw1h[i] = h; bw1l[i] = f2bf(w - bf2f(h));
    } else if (i < S1 + S2){
        int ii = i - S1;
        int fr = ii >> 9, r = ii & 511;
        int kt = fr >> 5, ct = fr & 31;
        int lane = r >> 3, j = r & 7;
        int k = kt*32 + ((lane>>4)<<3) + j;
        int n = lane & 15;
        int cell = ((ct>>2)<<4) + n, g = ct & 3;
        float w = (k<200 && cell<100) ? l2w[(size_t)k*400 + g*100 + cell] : 0.f;
        unsigned short h = f2bf(w);
        bw2h[ii] = h; bw2l[ii] = f2bf(w - bf2f(h));
    } else if (i < S1+S2+512){
        int col = i - S1 - S2;
        int ct = col >> 4, n = col & 15;
        int cell = ((ct>>2)<<4) + n, g = ct & 3;
        pbias1[col] = (cell<100) ? l1b[g*100+cell] : 0.f;
    } else if (i < S1+S2+1024){
        int col = i - S1 - S2 - 512;
        int ct = col >> 4, n = col & 15;
        int cell = ((ct>>2)<<4) + n, g = ct & 3;
        pbias2[col] = (cell<100) ? l2b[g*100+cell] : 0.f;
    }
}

// ---------------------------------------------------------------------------
// Kernel 4: PERSISTENT 2-layer LSTM + projection via split-bf16 MFMA, v3.
// R9's fully-unrolled kt loop hoisted ~190 B-frag loads -> VGPR 256 +
// scratch spills -> scratch thrashed per-XCD L2 -> the 0.77 MB weight set
// missed 30% -> 8.6 GB HBM fetch (HBM-bound, 4.1 ms). Fix: kt loop is
// #pragma unroll 1 (live set ~130 VGPRs: 32 acc + 64 B-frag + A regs) and
// __launch_bounds__(256,3) pins allocation; weight stream then stays
// L2-resident (~2 MB/CU/step at ~60 B/cyc ≈ 14 us/step).
// ---------------------------------------------------------------------------
#define KP1 164
#define KP2 228
__global__ __launch_bounds__(256, 3) void lstm_mfma2(
    const float* __restrict__ xall,   // [55][30][N]
    const unsigned short* __restrict__ bw1h, const unsigned short* __restrict__ bw1l,
    const unsigned short* __restrict__ bw2h, const unsigned short* __restrict__ bw2l,
    const float* __restrict__ pbias1, const float* __restrict__ pbias2,
    const float* __restrict__ we, const float* __restrict__ be,
    float* __restrict__ out)          // [N][55]
{
    __shared__ float A1[16*KP1];      // [m][k]: k<30 x_t, 30..129 h1, pad 0
    __shared__ float A2[16*KP2];      // [m][k]: k<100 h1new, 100..199 h2, pad 0
    __shared__ float pbuf[128];

    const int tid  = threadIdx.x;
    const int wave = tid >> 6, lane = tid & 63;
    const int m16  = lane & 15, quad = lane >> 4;
    const int n0   = blockIdx.x * 16;
    const int cl0  = wave*2;              // my 2 cell-tiles: cl0, cl0+1
    const int cell0 = cl0*16 + m16;
    const int cell1 = cell0 + 16;

    for (int i=tid; i<16*KP1; i+=256) A1[i]=0.f;
    for (int i=tid; i<16*KP2; i+=256) A2[i]=0.f;

    float cs1a[4]={0,0,0,0}, cs1b[4]={0,0,0,0};
    float cs2a[4]={0,0,0,0}, cs2b[4]={0,0,0,0};
    float b1a[4], b1b[4], b2a[4], b2b[4];
    #pragma unroll
    for (int g=0; g<4; g++){
        b1a[g] = pbias1[(cl0*4+g)*16 + m16];
        b1b[g] = pbias1[((cl0+1)*4+g)*16 + m16];
        b2a[g] = pbias2[(cl0*4+g)*16 + m16];
        b2b[g] = pbias2[((cl0+1)*4+g)*16 + m16];
    }
    __syncthreads();

    facc acA[4], acB[4];

// GEMM over NKT k-tiles. kt loop deliberately NOT unrolled (R9 spill fix);
// g loop unrolled (literal bounds -> acc stays in registers).
#define GEMM(WH, WL, NKT, ABUF, KP, BIA, BIB) \
    { _Pragma("unroll") \
      for (int g=0; g<4; g++){ \
          acA[g]=(facc){(BIA)[g],(BIA)[g],(BIA)[g],(BIA)[g]}; \
          acB[g]=(facc){(BIB)[g],(BIB)[g],(BIB)[g],(BIB)[g]}; } \
      _Pragma("unroll 1") \
      for (int kt=0; kt<(NKT); kt++){ \
        float av[8]; \
        const float* ap = (ABUF) + m16*(KP) + kt*32 + quad*8; \
        *(float4*)(av)   = *(const float4*)ap; \
        *(float4*)(av+4) = *(const float4*)(ap+4); \
        bfrag ah, al; \
        _Pragma("unroll") \
        for (int e=0;e<8;e++){ \
            unsigned short hh = f2bf(av[e]); \
            ah[e] = (short)hh; \
            al[e] = (short)f2bf(av[e] - bf2f(hh)); } \
        const unsigned short* whp = (WH) + ((size_t)(kt*32 + cl0*4)*64 + lane)*8; \
        const unsigned short* wlp = (WL) + ((size_t)(kt*32 + cl0*4)*64 + lane)*8; \
        _Pragma("unroll") \
        for (int g=0; g<4; g++){ \
          { bfrag bh = *(const bfrag*)(whp + (size_t)g*512); \
            bfrag bl = *(const bfrag*)(wlp + (size_t)g*512); \
            acA[g] = __builtin_amdgcn_mfma_f32_16x16x32_bf16(ah, bh, acA[g],0,0,0); \
            acA[g] = __builtin_amdgcn_mfma_f32_16x16x32_bf16(al, bh, acA[g],0,0,0); \
            acA[g] = __builtin_amdgcn_mfma_f32_16x16x32_bf16(ah, bl, acA[g],0,0,0); \
            acA[g] = __builtin_amdgcn_mfma_f32_16x16x32_bf16(al, bl, acA[g],0,0,0); } \
          { bfrag bh = *(const bfrag*)(whp + (size_t)(4+g)*512); \
            bfrag bl = *(const bfrag*)(wlp + (size_t)(4+g)*512); \
            acB[g] = __builtin_amdgcn_mfma_f32_16x16x32_bf16(ah, bh, acB[g],0,0,0); \
            acB[g] = __builtin_amdgcn_mfma_f32_16x16x32_bf16(al, bh, acB[g],0,0,0); \
            acB[g] = __builtin_amdgcn_mfma_f32_16x16x32_bf16(ah, bl, acB[g],0,0,0); \
            acB[g] = __builtin_amdgcn_mfma_f32_16x16x32_bf16(al, bl, acB[g],0,0,0); } \
        } \
      } }

#define EPI1(AC, CS, CELL) \
    { _Pragma("unroll") \
      for (int i2=0;i2<4;i2++){ \
        float gi = sigmoidf_((AC)[0][i2]); \
        float gj = tanhf((AC)[1][i2]); \
        float gf = sigmoidf_((AC)[2][i2] + 1.0f); \
        float go = sigmoidf_((AC)[3][i2]); \
        float cn = gf*(CS)[i2] + gi*gj; \
        (CS)[i2] = cn; \
        float h = go*tanhf(cn); \
        if ((CELL) < 100){ \
            int m = quad*4 + i2; \
            A1[m*KP1 + 30 + (CELL)] = h; \
            A2[m*KP2 + (CELL)] = h; } } }

#define EPI2(AC, CS, CELL) \
    { _Pragma("unroll") \
      for (int i2=0;i2<4;i2++){ \
        float gi = sigmoidf_((AC)[0][i2]); \
        float gj = tanhf((AC)[1][i2]); \
        float gf = sigmoidf_((AC)[2][i2] + 1.0f); \
        float go = sigmoidf_((AC)[3][i2]); \
        float cn = gf*(CS)[i2] + gi*gj; \
        (CS)[i2] = cn; \
        float h = go*tanhf(cn); \
        if ((CELL) < 100){ \
            int m = quad*4 + i2; \
            A2[m*KP2 + 100 + (CELL)] = h; } } }

    for (int t=0; t<T_SEQ; t++){
        // P1: stage x_t into A1 (k<30), transposed to [m][k]
        if (tid < 120){
            int k = tid >> 2, q = tid & 3;
            float4 v = *(const float4*)(xall + ((size_t)t*30+k)*N_ROWS + n0 + q*4);
            A1[(q*4+0)*KP1 + k] = v.x;
            A1[(q*4+1)*KP1 + k] = v.y;
            A1[(q*4+2)*KP1 + k] = v.z;
            A1[(q*4+3)*KP1 + k] = v.w;
        }
        __syncthreads();                                   // B1

        GEMM(bw1h, bw1l, 5, A1, KP1, b1a, b1b);            // layer 1
        __syncthreads();                                   // B2
        EPI1(acA, cs1a, cell0);
        EPI1(acB, cs1b, cell1);
        __syncthreads();                                   // B3

        GEMM(bw2h, bw2l, 7, A2, KP2, b2a, b2b);            // layer 2
        __syncthreads();                                   // B4
        EPI2(acA, cs2a, cell0);
        EPI2(acB, cs2b, cell1);
        __syncthreads();                                   // B5

        // P6: fused 1x1 projection out[n][t] = h2 . we + be
        if (tid < 128){
            int r = tid & 15, s = tid >> 4;
            int cb = s*13, ce = (s==7) ? 100 : cb+13;
            float p = 0.f;
            for (int cc=cb; cc<ce; cc++)
                p = fmaf(A2[r*KP2 + 100 + cc], we[cc], p);
            pbuf[tid] = p;
        }
        __syncthreads();                                   // B6
        if (tid < 16){
            float s = be[0];
            #pragma unroll
            for (int q2=0;q2<8;q2++) s += pbuf[q2*16 + tid];
            out[(size_t)(n0+tid)*T_SEQ + t] = s;
        }
    }
#undef GEMM
#undef EPI1
#undef EPI2
}

// ---------------------------------------------------------------------------
extern "C" void kernel_launch(void* const* d_in, const int* in_sizes, int n_in,
                              void* d_out, int out_size, void* d_ws, size_t ws_size,
                              hipStream_t stream)
{
    const float* x    = (const float*)d_in[0];
    const float* w10  = (const float*)d_in[1];  const float* b10 = (const float*)d_in[2];
    const float* w11  = (const float*)d_in[3];  const float* b11 = (const float*)d_in[4];
    const float* w12  = (const float*)d_in[5];  const float* b12 = (const float*)d_in[6];
    const float* w13  = (const float*)d_in[7];  const float* b13 = (const float*)d_in[8];
    const float* w20  = (const float*)d_in[9];  const float* b20 = (const float*)d_in[10];
    const float* w21  = (const float*)d_in[11]; const float* b21 = (const float*)d_in[12];
    const float* w22  = (const float*)d_in[13]; const float* b22 = (const float*)d_in[14];
    const float* w23  = (const float*)d_in[15]; const float* b23 = (const float*)d_in[16];
    const float* l1w  = (const float*)d_in[17]; const float* l1b = (const float*)d_in[18];
    const float* l2w  = (const float*)d_in[19]; const float* l2b = (const float*)d_in[20];
    const float* we   = (const float*)d_in[21]; const float* be  = (const float*)d_in[22];
    float* out = (float*)d_out;

    // workspace: conv slab 71.4 MB + packed bf16 weights ~0.8 MB + biases
    const size_t NF = (size_t)30*N_ROWS;
    float* buf0 = (float*)d_ws;                       // [55][30][N] floats
    unsigned short* bw1h = (unsigned short*)(buf0 + (size_t)T_SEQ*NF);
    unsigned short* bw1l = bw1h + 5*32*512;           // 81920 each
    unsigned short* bw2h = bw1l + 5*32*512;
    unsigned short* bw2l = bw2h + 7*32*512;           // 114688 each
    float* pbias1 = (float*)(bw2l + 7*32*512);
    float* pbias2 = pbias1 + 512;

    const int REPACK_N = 5*32*512 + 7*32*512 + 1024;
    repack_mfma<<<(REPACK_N+255)/256, 256, 0, stream>>>(
        l1w, l1b, l2w, l2b, bw1h, bw1l, bw2h, bw2l, pbias1, pbias2);

    dim3 g1((N_ROWS+255)/256, T_SEQ);
    conv1x1_chain<<<g1, 256, 0, stream>>>(x, w10,b10, w11,b11, w12,b12, w13,b13, buf0);
    conv5x5<<<T_SEQ*64, 192, 0, stream>>>(buf0, w20, b20);
    conv5x5<<<T_SEQ*64, 192, 0, stream>>>(buf0, w21, b21);
    conv5x5<<<T_SEQ*64, 192, 0, stream>>>(buf0, w22, b22);
    conv5x5<<<T_SEQ*64, 192, 0, stream>>>(buf0, w23, b23);

    lstm_mfma2<<<N_ROWS/16, 256, 0, stream>>>(buf0, bw1h, bw1l, bw2h, bw2l,
                                              pbias1, pbias2, we, be, out);
}